// Round 3
// baseline (546.436 us; speedup 1.0000x reference)
//
#include <hip/hip_runtime.h>

// Lowpass IIR scan: level[t] = (1-s)*x[t] + s*level[t-1], s = sigmoid(smooth).
// SINGLE-DISPATCH decoupled-lookback chunked scan (rocPRIM-style):
//   block (c,b) [256 thr = 256 float4 chain-groups of batch b]:
//     A: scan own chunk with zero entry -> partial P[c][b][:]
//        publish: threadfence + release flag  (block waits only on LOWER
//        blockIdx -> deadlock-free under in-order dispatch; additionally the
//        whole grid (512 blocks, 8 waves/CU) is co-resident)
//     lookback: acquire-spin on flags of chunks i<c (same b)
//     entry_c = level0*s^(L*c) + sum_i s^(L*(c-1-i)) P_i   (Horner, s^L const)
//     B: re-scan chunk (L2/L3-warm) with true entry, non-temporal stores.
// Flags zeroed by a 2 KiB hipMemsetAsync each replay (ws may be poisoned).

typedef float f32x4 __attribute__((ext_vector_type(4)));

constexpr int B   = 16;
constexpr int T   = 2048;
constexpr int U   = 1024;
constexpr int U4  = U / 4;        // 256 float4 per row
constexpr int BU4 = B * U4;       // 4096 chain-groups

__device__ __forceinline__ float sigmoidf(float x) {
    return 1.0f / (1.0f + __expf(-x));
}

// ======================= single-dispatch lookback =======================
template <int C>
__global__ __launch_bounds__(256, 2) void lowpass_lookback(
    const f32x4* __restrict__ in,      // [B*T*U4]
    const float* __restrict__ level0,  // [U]
    const float* __restrict__ smooth,  // [U]
    f32x4*       __restrict__ P,       // [C*BU4]
    unsigned*    __restrict__ flags,   // [C*B]
    f32x4*       __restrict__ out)     // [B*T*U4]
{
    constexpr int L  = T / C;
    constexpr int DA = 16;            // A-phase prefetch depth
    constexpr int DB = 8;             // B-phase prefetch depth (loads+stores)
    constexpr int LOG2L = 31 - __builtin_clz(L);
    static_assert(L % DA == 0 && L > DA, "A prefetch");
    static_assert(L % DB == 0 && L > DB, "B prefetch");
    static_assert((1 << LOG2L) == L, "pow2");

    const int c   = blockIdx.x >> 4;        // chunk (uniform per block)
    const int b   = blockIdx.x & 15;        // batch
    const int tid = (int)threadIdx.x;       // float4 column group 0..255
    const int lg  = b * U4 + tid;           // chain-group index

    const f32x4 sm = reinterpret_cast<const f32x4*>(smooth)[tid];
    const float s0 = sigmoidf(sm.x), s1 = sigmoidf(sm.y),
                s2 = sigmoidf(sm.z), s3 = sigmoidf(sm.w);
    const float o0 = 1.0f - s0, o1 = 1.0f - s1,
                o2 = 1.0f - s2, o3 = 1.0f - s3;

    const int base = (b * T + c * L) * U4 + tid;
    const f32x4* __restrict__ ip = in + base;

    // ---------------- Phase A: chunk partial (zero entry) ----------------
    float a0 = 0.0f, a1 = 0.0f, a2 = 0.0f, a3 = 0.0f;
    {
        f32x4 buf[DA];
        #pragma unroll
        for (int i = 0; i < DA; ++i) buf[i] = ip[i * U4];

        int t = 0;
        for (; t < L - DA; t += DA) {
            #pragma unroll
            for (int j = 0; j < DA; ++j) {
                f32x4 x = buf[j];
                buf[j] = ip[(t + DA + j) * U4];
                a0 = fmaf(s0, a0, o0 * x.x);
                a1 = fmaf(s1, a1, o1 * x.y);
                a2 = fmaf(s2, a2, o2 * x.z);
                a3 = fmaf(s3, a3, o3 * x.w);
            }
        }
        #pragma unroll
        for (int j = 0; j < DA; ++j) {
            f32x4 x = buf[j];
            a0 = fmaf(s0, a0, o0 * x.x);
            a1 = fmaf(s1, a1, o1 * x.y);
            a2 = fmaf(s2, a2, o2 * x.z);
            a3 = fmaf(s3, a3, o3 * x.w);
        }
    }
    f32x4 part; part.x = a0; part.y = a1; part.z = a2; part.w = a3;
    P[c * BU4 + lg] = part;

    // publish: all threads' P stores device-visible before the flag
    __threadfence();
    __syncthreads();
    if (tid == 0) {
        __hip_atomic_store(&flags[blockIdx.x], 1u,
                           __ATOMIC_RELEASE, __HIP_MEMORY_SCOPE_AGENT);
    }

    // ---------------- lookback: wait for chunks i < c (same b) -----------
    // per-thread acquire so every thread's subsequent P reads are ordered
    for (int i = 0; i < c; ++i) {
        while (__hip_atomic_load(&flags[i * 16 + b],
                                 __ATOMIC_ACQUIRE, __HIP_MEMORY_SCOPE_AGENT) == 0u) {
            __builtin_amdgcn_s_sleep(1);
        }
    }

    // entry level: Horner with sL = s^L (repeated squaring)
    float sL0 = s0, sL1 = s1, sL2 = s2, sL3 = s3;
    #pragma unroll
    for (int i = 0; i < LOG2L; ++i) {
        sL0 *= sL0; sL1 *= sL1; sL2 *= sL2; sL3 *= sL3;
    }
    const f32x4 l0 = reinterpret_cast<const f32x4*>(level0)[tid];
    float v0 = l0.x, v1 = l0.y, v2 = l0.z, v3 = l0.w;
    for (int i = 0; i < c; ++i) {
        f32x4 p = P[i * BU4 + lg];
        v0 = fmaf(sL0, v0, p.x);
        v1 = fmaf(sL1, v1, p.y);
        v2 = fmaf(sL2, v2, p.z);
        v3 = fmaf(sL3, v3, p.w);
    }

    // ---------------- Phase B: scan + store (input L2/L3-warm) -----------
    f32x4* __restrict__ op = out + base;
    f32x4 buf[DB];
    #pragma unroll
    for (int i = 0; i < DB; ++i) buf[i] = ip[i * U4];

    int t = 0;
    for (; t < L - DB; t += DB) {
        #pragma unroll
        for (int j = 0; j < DB; ++j) {
            f32x4 x = buf[j];
            buf[j] = ip[(t + DB + j) * U4];
            v0 = fmaf(s0, v0, o0 * x.x);
            v1 = fmaf(s1, v1, o1 * x.y);
            v2 = fmaf(s2, v2, o2 * x.z);
            v3 = fmaf(s3, v3, o3 * x.w);
            f32x4 r; r.x = v0; r.y = v1; r.z = v2; r.w = v3;
            __builtin_nontemporal_store(r, &op[(t + j) * U4]);
        }
    }
    #pragma unroll
    for (int j = 0; j < DB; ++j) {
        f32x4 x = buf[j];
        v0 = fmaf(s0, v0, o0 * x.x);
        v1 = fmaf(s1, v1, o1 * x.y);
        v2 = fmaf(s2, v2, o2 * x.z);
        v3 = fmaf(s3, v3, o3 * x.w);
        f32x4 r; r.x = v0; r.y = v1; r.z = v2; r.w = v3;
        __builtin_nontemporal_store(r, &op[(t + j) * U4]);
    }
}

// ================= fallback: proven two-kernel version =================
template <int C>
__global__ __launch_bounds__(64) void lowpass_partial(
    const f32x4* __restrict__ in, const float* __restrict__ smooth,
    f32x4* __restrict__ P)
{
    constexpr int L  = T / C;
    constexpr int D1 = 16;
    const int tid = blockIdx.x * 64 + (int)threadIdx.x;
    const int c  = tid >> 12;
    const int lg = tid & (BU4 - 1);
    const int b  = lg >> 8;
    const int ug = lg & (U4 - 1);

    const f32x4 sm = reinterpret_cast<const f32x4*>(smooth)[ug];
    const float s0 = sigmoidf(sm.x), s1 = sigmoidf(sm.y),
                s2 = sigmoidf(sm.z), s3 = sigmoidf(sm.w);
    const float o0 = 1.0f - s0, o1 = 1.0f - s1,
                o2 = 1.0f - s2, o3 = 1.0f - s3;

    const f32x4* __restrict__ ip = in + (b * T + c * L) * U4 + ug;
    float a0 = 0, a1 = 0, a2 = 0, a3 = 0;
    f32x4 buf[D1];
    #pragma unroll
    for (int i = 0; i < D1; ++i) buf[i] = ip[i * U4];
    int t = 0;
    for (; t < L - D1; t += D1) {
        #pragma unroll
        for (int j = 0; j < D1; ++j) {
            f32x4 x = buf[j];
            buf[j] = ip[(t + D1 + j) * U4];
            a0 = fmaf(s0, a0, o0 * x.x); a1 = fmaf(s1, a1, o1 * x.y);
            a2 = fmaf(s2, a2, o2 * x.z); a3 = fmaf(s3, a3, o3 * x.w);
        }
    }
    #pragma unroll
    for (int j = 0; j < D1; ++j) {
        f32x4 x = buf[j];
        a0 = fmaf(s0, a0, o0 * x.x); a1 = fmaf(s1, a1, o1 * x.y);
        a2 = fmaf(s2, a2, o2 * x.z); a3 = fmaf(s3, a3, o3 * x.w);
    }
    f32x4 part; part.x = a0; part.y = a1; part.z = a2; part.w = a3;
    P[c * BU4 + lg] = part;
}

template <int C>
__global__ __launch_bounds__(64) void lowpass_scan(
    const f32x4* __restrict__ in, const float* __restrict__ level0,
    const float* __restrict__ smooth, const f32x4* __restrict__ P,
    f32x4* __restrict__ out)
{
    constexpr int L  = T / C;
    constexpr int D2 = 8;
    constexpr int LOG2L = 31 - __builtin_clz(L);
    const int tid = blockIdx.x * 64 + (int)threadIdx.x;
    const int c  = tid >> 12;
    const int lg = tid & (BU4 - 1);
    const int b  = lg >> 8;
    const int ug = lg & (U4 - 1);

    const f32x4 sm = reinterpret_cast<const f32x4*>(smooth)[ug];
    const float s0 = sigmoidf(sm.x), s1 = sigmoidf(sm.y),
                s2 = sigmoidf(sm.z), s3 = sigmoidf(sm.w);
    const float o0 = 1.0f - s0, o1 = 1.0f - s1,
                o2 = 1.0f - s2, o3 = 1.0f - s3;

    float sL0 = s0, sL1 = s1, sL2 = s2, sL3 = s3;
    #pragma unroll
    for (int i = 0; i < LOG2L; ++i) { sL0*=sL0; sL1*=sL1; sL2*=sL2; sL3*=sL3; }

    const f32x4 l0 = reinterpret_cast<const f32x4*>(level0)[ug];
    float v0 = l0.x, v1 = l0.y, v2 = l0.z, v3 = l0.w;
    for (int i = 0; i < c; ++i) {
        f32x4 p = P[i * BU4 + lg];
        v0 = fmaf(sL0, v0, p.x); v1 = fmaf(sL1, v1, p.y);
        v2 = fmaf(sL2, v2, p.z); v3 = fmaf(sL3, v3, p.w);
    }

    const int base = (b * T + c * L) * U4 + ug;
    const f32x4* __restrict__ ip = in + base;
    f32x4* __restrict__ op = out + base;
    f32x4 buf[D2];
    #pragma unroll
    for (int i = 0; i < D2; ++i) buf[i] = ip[i * U4];
    int t = 0;
    for (; t < L - D2; t += D2) {
        #pragma unroll
        for (int j = 0; j < D2; ++j) {
            f32x4 x = buf[j];
            buf[j] = ip[(t + D2 + j) * U4];
            v0 = fmaf(s0, v0, o0 * x.x); v1 = fmaf(s1, v1, o1 * x.y);
            v2 = fmaf(s2, v2, o2 * x.z); v3 = fmaf(s3, v3, o3 * x.w);
            f32x4 r; r.x = v0; r.y = v1; r.z = v2; r.w = v3;
            __builtin_nontemporal_store(r, &op[(t + j) * U4]);
        }
    }
    #pragma unroll
    for (int j = 0; j < D2; ++j) {
        f32x4 x = buf[j];
        v0 = fmaf(s0, v0, o0 * x.x); v1 = fmaf(s1, v1, o1 * x.y);
        v2 = fmaf(s2, v2, o2 * x.z); v3 = fmaf(s3, v3, o3 * x.w);
        f32x4 r; r.x = v0; r.y = v1; r.z = v2; r.w = v3;
        __builtin_nontemporal_store(r, &op[(t + j) * U4]);
    }
}

extern "C" void kernel_launch(void* const* d_in, const int* in_sizes, int n_in,
                              void* d_out, int out_size, void* d_ws, size_t ws_size,
                              hipStream_t stream) {
    const f32x4* in     = (const f32x4*)d_in[0];  // inputs [B,T,U]
    const float* level0 = (const float*)d_in[1];  // level_var [1,U]
    const float* smooth = (const float*)d_in[2];  // smoothing_var [1,U]
    f32x4* out          = (f32x4*)d_out;
    f32x4* P            = (f32x4*)d_ws;

    const size_t pBytes32 = (size_t)32 * BU4 * sizeof(f32x4);  // 2 MiB
    const size_t pBytes16 = (size_t)16 * BU4 * sizeof(f32x4);  // 1 MiB

    if (ws_size >= pBytes32 + 32 * B * sizeof(unsigned)) {
        constexpr int C = 32;
        unsigned* flags = (unsigned*)((char*)d_ws + pBytes32);
        hipMemsetAsync(flags, 0, C * B * sizeof(unsigned), stream);
        hipLaunchKernelGGL(lowpass_lookback<C>, dim3(C * B), dim3(256), 0, stream,
                           in, level0, smooth, P, flags, out);
    } else if (ws_size >= pBytes16 + 16 * B * sizeof(unsigned)) {
        constexpr int C = 16;
        unsigned* flags = (unsigned*)((char*)d_ws + pBytes16);
        hipMemsetAsync(flags, 0, C * B * sizeof(unsigned), stream);
        hipLaunchKernelGGL(lowpass_lookback<C>, dim3(C * B), dim3(256), 0, stream,
                           in, level0, smooth, P, flags, out);
    } else {
        constexpr int C = 8;   // proven-safe fallback (512 KiB workspace)
        dim3 block(64);
        dim3 grid(C * BU4 / 64);
        hipLaunchKernelGGL(lowpass_partial<C>, grid, block, 0, stream, in, smooth, P);
        hipLaunchKernelGGL(lowpass_scan<C>,    grid, block, 0, stream, in, level0, smooth, P, out);
    }
}

// Round 4
// 250.564 us; speedup vs baseline: 2.1808x; 2.1808x over previous
//
#include <hip/hip_runtime.h>

// Lowpass IIR scan: level[t] = (1-s)*x[t] + s*level[t-1], s = sigmoid(smooth).
// Two-kernel chunked-scan decomposition, C=32 chunks, 256-thread full-row
// blocks (each block = one (batch, chunk) pair; 256 float4 = full U row).
//   K1: per-chunk partial finals P_c (zero-entry scan). Pure streaming read.
//   K2: entry_c = Horner(P_0..P_{c-1}, s^L) + s^{Lc}*level0 in-register,
//       then scan + store chunk. Input re-read is L3-warm (proven R3:
//       FETCH=132MB total). Non-temporal stores keep out of the caches.
// In-kernel inter-block sync was tried (R3) and cost 250+ us in acquire
// invalidation storms -> kernel boundary is the cheaper barrier.

typedef float f32x4 __attribute__((ext_vector_type(4)));

constexpr int B   = 16;
constexpr int T   = 2048;
constexpr int U   = 1024;
constexpr int U4  = U / 4;        // 256 float4 per row
constexpr int BU4 = B * U4;       // 4096 chain-groups

__device__ __forceinline__ float sigmoidf(float x) {
    return 1.0f / (1.0f + __expf(-x));
}

// ---- Kernel 1: per-chunk partial finals P[c][b][ug] (zero entry) ----
template <int C>
__global__ __launch_bounds__(256, 2) void lowpass_partial(
    const f32x4* __restrict__ in,      // [B*T*U4]
    const float* __restrict__ smooth,  // [U]
    f32x4*       __restrict__ P)       // [C*BU4]
{
    constexpr int L  = T / C;
    constexpr int DA = 16;            // prefetch depth (loads only)
    static_assert(L % DA == 0 && L > DA, "A prefetch");

    const int c   = blockIdx.x >> 4;        // chunk
    const int b   = blockIdx.x & 15;        // batch
    const int tid = (int)threadIdx.x;       // float4 column 0..255
    const int lg  = b * U4 + tid;

    const f32x4 sm = reinterpret_cast<const f32x4*>(smooth)[tid];
    const float s0 = sigmoidf(sm.x), s1 = sigmoidf(sm.y),
                s2 = sigmoidf(sm.z), s3 = sigmoidf(sm.w);
    const float o0 = 1.0f - s0, o1 = 1.0f - s1,
                o2 = 1.0f - s2, o3 = 1.0f - s3;

    const f32x4* __restrict__ ip = in + (b * T + c * L) * U4 + tid;

    float a0 = 0.0f, a1 = 0.0f, a2 = 0.0f, a3 = 0.0f;
    f32x4 buf[DA];
    #pragma unroll
    for (int i = 0; i < DA; ++i) buf[i] = ip[i * U4];

    int t = 0;
    for (; t < L - DA; t += DA) {
        #pragma unroll
        for (int j = 0; j < DA; ++j) {
            f32x4 x = buf[j];
            buf[j] = ip[(t + DA + j) * U4];
            a0 = fmaf(s0, a0, o0 * x.x);
            a1 = fmaf(s1, a1, o1 * x.y);
            a2 = fmaf(s2, a2, o2 * x.z);
            a3 = fmaf(s3, a3, o3 * x.w);
        }
    }
    #pragma unroll
    for (int j = 0; j < DA; ++j) {
        f32x4 x = buf[j];
        a0 = fmaf(s0, a0, o0 * x.x);
        a1 = fmaf(s1, a1, o1 * x.y);
        a2 = fmaf(s2, a2, o2 * x.z);
        a3 = fmaf(s3, a3, o3 * x.w);
    }
    f32x4 part; part.x = a0; part.y = a1; part.z = a2; part.w = a3;
    P[c * BU4 + lg] = part;
}

// ---- Kernel 2: recombine entry level, scan chunk, store ----
template <int C>
__global__ __launch_bounds__(256, 2) void lowpass_scan(
    const f32x4* __restrict__ in,      // [B*T*U4]
    const float* __restrict__ level0,  // [U]
    const float* __restrict__ smooth,  // [U]
    const f32x4* __restrict__ P,       // [C*BU4]
    f32x4*       __restrict__ out)     // [B*T*U4]
{
    constexpr int L  = T / C;
    constexpr int DB = 8;             // prefetch depth (loads+stores share vmcnt)
    constexpr int LOG2L = 31 - __builtin_clz(L);
    static_assert(L % DB == 0 && L > DB, "B prefetch");
    static_assert((1 << LOG2L) == L, "pow2");

    const int c   = blockIdx.x >> 4;
    const int b   = blockIdx.x & 15;
    const int tid = (int)threadIdx.x;
    const int lg  = b * U4 + tid;

    const f32x4 sm = reinterpret_cast<const f32x4*>(smooth)[tid];
    const float s0 = sigmoidf(sm.x), s1 = sigmoidf(sm.y),
                s2 = sigmoidf(sm.z), s3 = sigmoidf(sm.w);
    const float o0 = 1.0f - s0, o1 = 1.0f - s1,
                o2 = 1.0f - s2, o3 = 1.0f - s3;

    // s^L via repeated squaring
    float sL0 = s0, sL1 = s1, sL2 = s2, sL3 = s3;
    #pragma unroll
    for (int i = 0; i < LOG2L; ++i) {
        sL0 *= sL0; sL1 *= sL1; sL2 *= sL2; sL3 *= sL3;
    }

    // entry level: Horner over preceding chunk partials
    const f32x4 l0 = reinterpret_cast<const f32x4*>(level0)[tid];
    float v0 = l0.x, v1 = l0.y, v2 = l0.z, v3 = l0.w;
    for (int i = 0; i < c; ++i) {          // uniform trip count per block
        f32x4 p = P[i * BU4 + lg];
        v0 = fmaf(sL0, v0, p.x);
        v1 = fmaf(sL1, v1, p.y);
        v2 = fmaf(sL2, v2, p.z);
        v3 = fmaf(sL3, v3, p.w);
    }

    const int base = (b * T + c * L) * U4 + tid;
    const f32x4* __restrict__ ip = in  + base;
    f32x4*       __restrict__ op = out + base;

    f32x4 buf[DB];
    #pragma unroll
    for (int i = 0; i < DB; ++i) buf[i] = ip[i * U4];

    int t = 0;
    for (; t < L - DB; t += DB) {
        #pragma unroll
        for (int j = 0; j < DB; ++j) {
            f32x4 x = buf[j];
            buf[j] = ip[(t + DB + j) * U4];
            v0 = fmaf(s0, v0, o0 * x.x);
            v1 = fmaf(s1, v1, o1 * x.y);
            v2 = fmaf(s2, v2, o2 * x.z);
            v3 = fmaf(s3, v3, o3 * x.w);
            f32x4 r; r.x = v0; r.y = v1; r.z = v2; r.w = v3;
            __builtin_nontemporal_store(r, &op[(t + j) * U4]);
        }
    }
    #pragma unroll
    for (int j = 0; j < DB; ++j) {
        f32x4 x = buf[j];
        v0 = fmaf(s0, v0, o0 * x.x);
        v1 = fmaf(s1, v1, o1 * x.y);
        v2 = fmaf(s2, v2, o2 * x.z);
        v3 = fmaf(s3, v3, o3 * x.w);
        f32x4 r; r.x = v0; r.y = v1; r.z = v2; r.w = v3;
        __builtin_nontemporal_store(r, &op[(t + j) * U4]);
    }
}

extern "C" void kernel_launch(void* const* d_in, const int* in_sizes, int n_in,
                              void* d_out, int out_size, void* d_ws, size_t ws_size,
                              hipStream_t stream) {
    const f32x4* in     = (const f32x4*)d_in[0];  // inputs [B,T,U]
    const float* level0 = (const float*)d_in[1];  // level_var [1,U]
    const float* smooth = (const float*)d_in[2];  // smoothing_var [1,U]
    f32x4* out          = (f32x4*)d_out;
    f32x4* P            = (f32x4*)d_ws;

    if (ws_size >= (size_t)32 * BU4 * sizeof(f32x4)) {   // 2 MiB (proven R3)
        constexpr int C = 32;
        dim3 grid(C * B);    // 512 blocks x 256 thr = 2048 waves = 8/CU
        hipLaunchKernelGGL(lowpass_partial<C>, grid, dim3(256), 0, stream,
                           in, smooth, P);
        hipLaunchKernelGGL(lowpass_scan<C>,    grid, dim3(256), 0, stream,
                           in, level0, smooth, P, out);
    } else {                                              // 512 KiB fallback
        constexpr int C = 8;
        dim3 grid(C * B);    // 128 blocks
        hipLaunchKernelGGL(lowpass_partial<C>, grid, dim3(256), 0, stream,
                           in, smooth, P);
        hipLaunchKernelGGL(lowpass_scan<C>,    grid, dim3(256), 0, stream,
                           in, level0, smooth, P, out);
    }
}